// Round 7
// baseline (1170.413 us; speedup 1.0000x reference)
//
#include <hip/hip_runtime.h>
#include <math.h>

#define B_ 64
#define T_ 512
#define E_ 64
#define H_ 128
#define NH_ 8
#define KD_ 32
#define BT_ (B_ * T_)
#define NEG_ -1e9f

typedef __attribute__((ext_vector_type(8))) short bf16x8_t;
typedef __attribute__((ext_vector_type(4))) float f32x4_t;
typedef __attribute__((ext_vector_type(2))) float f32x2_t;
typedef unsigned short ushort_t;
typedef unsigned int uint_t;

__device__ __forceinline__ float sigmoidf_(float x) {
    return 1.f / (1.f + __expf(-x));
}
__device__ __forceinline__ float tanhf_(float x) {
    return 1.f - 2.f / (1.f + __expf(2.f * x));
}

__device__ __forceinline__ ushort_t bf16_rne(float x) {
    uint_t u = __float_as_uint(x);
    uint_t r = (u + 0x7FFFu + ((u >> 16) & 1u)) >> 16;
    return (ushort_t)r;
}
__device__ __forceinline__ float bf16_to_f(ushort_t h) {
    return __uint_as_float(((uint_t)h) << 16);
}
__device__ __forceinline__ void split_bf16(float x, ushort_t& h, ushort_t& l) {
    h = bf16_rne(x);
    l = bf16_rne(x - bf16_to_f(h));
}

// DPP quad-perm lane swaps: xor1 = [1,0,3,2], xor2 = [2,3,0,1]
__device__ __forceinline__ float qswap1(float x) {
    return __int_as_float(__builtin_amdgcn_mov_dpp(__float_as_int(x), 0xB1, 0xF, 0xF, true));
}
__device__ __forceinline__ float qswap2(float x) {
    return __int_as_float(__builtin_amdgcn_mov_dpp(__float_as_int(x), 0x4E, 0xF, 0xF, true));
}
// lane xor 4 via ds_swizzle (BitMode: xor=4, and=0x1F)
__device__ __forceinline__ float swz4(float x) {
    return __int_as_float(__builtin_amdgcn_ds_swizzle(__float_as_int(x), 0x101F));
}

// ---------------------------------------------------------------------------
// Prep:
//  blk 0..1023   : weight transpose + bf16 hi/lo split.
//                  m = blk>>8: 0..2 -> Wq/Wk/Wv stacked; m==3 -> Wo.
//  blk 1024..1027: embW tables embW[v][jj*4+g] = (emb[v] @ W + b), unit-major.
//  blk 1028      : stacked qkv bias (bq|bk|bv).
// ---------------------------------------------------------------------------
__global__ void prep_kernel(
    const float* __restrict__ emb,
    const float* __restrict__ Wf, const float* __restrict__ bf,
    const float* __restrict__ Wb, const float* __restrict__ bb,
    const float* __restrict__ Wq, const float* __restrict__ Wk,
    const float* __restrict__ Wv, const float* __restrict__ Wo,
    const float* __restrict__ bq, const float* __restrict__ bk,
    const float* __restrict__ bv,
    ushort_t* __restrict__ wqkvh, ushort_t* __restrict__ wqkvl,
    ushort_t* __restrict__ woh, ushort_t* __restrict__ wol,
    float* __restrict__ embWf, float* __restrict__ embWb,
    float* __restrict__ qkvb)
{
    const int blk = blockIdx.x, tid = threadIdx.x;
    if (blk < 1024) {
        const int m = blk >> 8, k = blk & 255;
        const float* W = (m == 0) ? Wq : (m == 1) ? Wk : (m == 2) ? Wv : Wo;
        float v = W[k * 256 + tid];
        ushort_t h, l;
        split_bf16(v, h, l);
        if (m < 3) {
            wqkvh[(m * 256 + tid) * 256 + k] = h;
            wqkvl[(m * 256 + tid) * 256 + k] = l;
        } else {
            woh[tid * 256 + k] = h;
            wol[tid * 256 + k] = l;
        }
    } else if (blk < 1028) {
        const int e = blk - 1024;
        const int dir = e >> 1, half = e & 1;
        const float* W = dir ? Wb : Wf;
        const float* bias = dir ? bb : bf;
        float* dst = dir ? embWb : embWf;
        const int np = half * 256 + tid;          // output col 0..511
        const int gin = ((np & 3) << 7) + (np >> 2);
        for (int v = 0; v < 20; ++v) {
            float acc = bias[gin];
            for (int k = 0; k < 64; ++k)
                acc = fmaf(emb[v * 64 + k], W[k * 512 + gin], acc);
            dst[v * 512 + np] = acc;
        }
    } else {
        qkvb[tid] = bq[tid];
        qkvb[256 + tid] = bk[tid];
        qkvb[512 + tid] = bv[tid];
    }
}

// ---------------------------------------------------------------------------
// bf16x3 MFMA GEMM: C[M][N] = A@B + bias, K=256 fixed. (verified r4-r6)
// ---------------------------------------------------------------------------
__global__ __launch_bounds__(256, 2) void gemm_mfma3(
    const ushort_t* __restrict__ Ah, const ushort_t* __restrict__ Al,
    const ushort_t* __restrict__ Bh, const ushort_t* __restrict__ Bl,
    const float* __restrict__ bias, float* __restrict__ C,
    int M, int N)
{
    __shared__ __align__(16) ushort_t Alds[2][128 * 40];
    __shared__ __align__(16) ushort_t Blds[2][128 * 40];

    const int tid = threadIdx.x;
    const int ntn = N >> 7;
    const int bm = blockIdx.x / ntn, bn = blockIdx.x % ntn;
    const int m0 = bm << 7, n0 = bn << 7;

    const int w = tid >> 6;
    const int wr = w >> 1, wc = w & 1;
    const int lane = tid & 63;
    const int fr = lane & 15, kg = lane >> 4;

    const int sr = tid >> 1;
    const int sh = (tid & 1) << 4;

    f32x4_t acc[4][4];
#pragma unroll
    for (int i = 0; i < 4; ++i)
#pragma unroll
        for (int j = 0; j < 4; ++j) acc[i][j] = (f32x4_t){0.f, 0.f, 0.f, 0.f};

    for (int ks = 0; ks < 8; ++ks) {
        const int k0 = ks << 5;
        __syncthreads();
        {
            const size_t ga = (size_t)(m0 + sr) * 256 + k0 + sh;
            const size_t gb = (size_t)(n0 + sr) * 256 + k0 + sh;
            const int ld = sr * 40 + sh;
            const uint4* pah = (const uint4*)(Ah + ga);
            const uint4* pal = (const uint4*)(Al + ga);
            const uint4* pbh = (const uint4*)(Bh + gb);
            const uint4* pbl = (const uint4*)(Bl + gb);
            uint4* qah = (uint4*)&Alds[0][ld];
            uint4* qal = (uint4*)&Alds[1][ld];
            uint4* qbh = (uint4*)&Blds[0][ld];
            uint4* qbl = (uint4*)&Blds[1][ld];
            qah[0] = pah[0]; qah[1] = pah[1];
            qal[0] = pal[0]; qal[1] = pal[1];
            qbh[0] = pbh[0]; qbh[1] = pbh[1];
            qbl[0] = pbl[0]; qbl[1] = pbl[1];
        }
        __syncthreads();

        bf16x8_t ah[4], al[4], bh[4], bl[4];
#pragma unroll
        for (int i = 0; i < 4; ++i) {
            const int ra = (wr * 64 + i * 16 + fr) * 40 + kg * 8;
            const int rb = (wc * 64 + i * 16 + fr) * 40 + kg * 8;
            ah[i] = *(const bf16x8_t*)&Alds[0][ra];
            al[i] = *(const bf16x8_t*)&Alds[1][ra];
            bh[i] = *(const bf16x8_t*)&Blds[0][rb];
            bl[i] = *(const bf16x8_t*)&Blds[1][rb];
        }
#pragma unroll
        for (int i = 0; i < 4; ++i)
#pragma unroll
            for (int j = 0; j < 4; ++j) {
                acc[i][j] = __builtin_amdgcn_mfma_f32_16x16x32_bf16(
                    ah[i], bh[j], acc[i][j], 0, 0, 0);
                acc[i][j] = __builtin_amdgcn_mfma_f32_16x16x32_bf16(
                    ah[i], bl[j], acc[i][j], 0, 0, 0);
                acc[i][j] = __builtin_amdgcn_mfma_f32_16x16x32_bf16(
                    al[i], bh[j], acc[i][j], 0, 0, 0);
            }
    }

#pragma unroll
    for (int j = 0; j < 4; ++j) {
        const int col = n0 + wc * 64 + j * 16 + fr;
        const float bv = bias[col];
#pragma unroll
        for (int i = 0; i < 4; ++i) {
#pragma unroll
            for (int r = 0; r < 4; ++r) {
                const int row = m0 + wr * 64 + i * 16 + kg * 4 + r;
                C[(size_t)row * N + col] = acc[i][j][r] + bv;
            }
        }
    }
}

// ---------------------------------------------------------------------------
// Bidirectional LSTM scan. One WG per (batch, dir): 128 WGs, 1024 threads.
// launch_bounds(1024,4) -> hard 128-reg/wave cap, so u2 (64 VGPRs) MUST live
// in arch VGPRs (r2-r6 failure mode: at 256-reg budget the allocator parked
// u in AGPRs with a copy per use). Thread (jj = tid>>3, ks = tid&7) computes
// 4 gates of unit jj over k-chunk [16ks, 16ks+16). 8-lane butterfly reduce =
// 2 DPP quad swaps + 1 ds_swizzle(xor4). Tail computed redundantly by all 8
// lanes (no divergence); ks==0 lane writes. Raw lgkmcnt-only barrier leaves
// the global h-stores and embW prefetch in flight (r5 bottleneck: the
// compiler's vmcnt(0) drain at __syncthreads cost ~1400 stall cyc/step).
// ---------------------------------------------------------------------------
__global__ __launch_bounds__(1024, 4) void lstm_scan(
    const int* __restrict__ seq,
    const float* __restrict__ embWf, const float* __restrict__ embWb,
    const float* __restrict__ Uf, const float* __restrict__ Ub,
    ushort_t* __restrict__ hch, ushort_t* __restrict__ hcl)
{
    const int w = blockIdx.x;
    const int dir = w & 1, b = w >> 1;
    const float* eW = dir ? embWb : embWf;
    const float* U  = dir ? Ub  : Uf;
    const int tid = threadIdx.x;
    const int jj = tid >> 3, ks = tid & 7;

    __shared__ __align__(16) float hbuf[2][8][20];  // padded: stride 20 floats
    __shared__ int tkl[T_];

    // u2[g][c] = (U[16ks+2c][g*128+jj], U[16ks+2c+1][g*128+jj])
    f32x2_t u2[4][8];
#pragma unroll
    for (int g = 0; g < 4; ++g)
#pragma unroll
        for (int c = 0; c < 8; ++c) {
            const int kb_ = 16 * ks + 2 * c;
            u2[g][c] = (f32x2_t){
                U[(size_t)kb_ * 512 + g * 128 + jj],
                U[(size_t)(kb_ + 1) * 512 + g * 128 + jj] };
        }

    if (tid < T_) tkl[tid] = seq[b * T_ + tid];
    if (tid < 2 * 8 * 20) ((float*)hbuf)[tid] = 0.f;

    float h_cur = 0.f, c_cur = 0.f;
    ushort_t* hoh = hch + (size_t)b * T_ * 256 + dir * 128;
    ushort_t* hol = hcl + (size_t)b * T_ * 256 + dir * 128;

    __syncthreads();

    int te = dir ? (T_ - 1) : 0;
    int tok = tkl[te];
    float4 xwv = *(const float4*)&eW[tok * 512 + jj * 4];

    int p = 0;
    for (int t = 0; t < T_; ++t) {
        const int te_n  = dir ? (te - 1) : (te + 1);
        const int te_pf = (t == T_ - 1) ? te : te_n;
        const int tok_n = tkl[te_pf];
        const float4 xw_n = *(const float4*)&eW[tok_n * 512 + jj * 4];

        f32x2_t ac0 = {0.f, 0.f}, ac1 = {0.f, 0.f};
        f32x2_t ac2 = {0.f, 0.f}, ac3 = {0.f, 0.f};
        const f32x2_t* hc2 = (const f32x2_t*)&hbuf[p][ks][0];
#pragma unroll
        for (int c = 0; c < 8; ++c) {
            const f32x2_t h2 = hc2[c];
            ac0 = __builtin_elementwise_fma(h2, u2[0][c], ac0);
            ac1 = __builtin_elementwise_fma(h2, u2[1][c], ac1);
            ac2 = __builtin_elementwise_fma(h2, u2[2][c], ac2);
            ac3 = __builtin_elementwise_fma(h2, u2[3][c], ac3);
        }
        float a0 = ac0.x + ac0.y, a1 = ac1.x + ac1.y;
        float a2 = ac2.x + ac2.y, a3 = ac3.x + ac3.y;
        // 8-lane butterfly: xor1 (DPP), xor2 (DPP), xor4 (ds_swizzle)
        a0 += qswap1(a0); a1 += qswap1(a1);
        a2 += qswap1(a2); a3 += qswap1(a3);
        a0 += qswap2(a0); a1 += qswap2(a1);
        a2 += qswap2(a2); a3 += qswap2(a3);
        a0 += swz4(a0); a1 += swz4(a1);
        a2 += swz4(a2); a3 += swz4(a3);

        // all 8 lanes compute the tail redundantly (identical inputs)
        const float zi = xwv.x + a0, zf = xwv.y + a1;
        const float zg = xwv.z + a2, zo = xwv.w + a3;
        const float cn = fmaf(sigmoidf_(zf), c_cur, sigmoidf_(zi) * tanhf_(zg));
        const float hn = sigmoidf_(zo) * tanhf_(cn);
        const bool mt = (tok != 0);
        const float hm = mt ? hn : h_cur;
        c_cur = mt ? cn : c_cur;
        h_cur = hm;

        if (ks == 0) {
            hbuf[1 - p][jj >> 4][jj & 15] = hm;
            ushort_t hh, hl;
            split_bf16(hm, hh, hl);
            hoh[(size_t)te * 256 + jj] = hh;
            hol[(size_t)te * 256 + jj] = hl;
        }
        // LDS-only drain + barrier: global stores/prefetch stay in flight.
        asm volatile("s_waitcnt lgkmcnt(0)\n\ts_barrier" ::: "memory");
        p ^= 1; te = te_n; tok = tok_n; xwv = xw_n;
    }
}

// ---------------------------------------------------------------------------
// Fused flash-style attention. One WG per (b, head): 512 WGs, 256 threads.
// q/k/v packed in one [BT][768] buffer (cols: q 0..255, k 256..511, v 512..).
// ---------------------------------------------------------------------------
__global__ __launch_bounds__(256, 2) void attn_fused(
    const int* __restrict__ seq,
    const float* __restrict__ qkv,
    ushort_t* __restrict__ cxh, ushort_t* __restrict__ cxl)
{
    const int wg = blockIdx.x;
    const int b = wg >> 3, h = wg & 7;
    const int tid = threadIdx.x;

    __shared__ __align__(16) float Ks[16][32];
    __shared__ __align__(16) float Vs[16][32];
    __shared__ float mk[16];

    float qA[32], qB[32];
    {
        const float* qp  = qkv + ((size_t)(b * T_) + tid) * 768 + h * KD_;
        const float* qp2 = qp + (size_t)256 * 768;
#pragma unroll
        for (int k = 0; k < 32; k += 4) {
            float4 v0 = *(const float4*)(qp + k);
            float4 v1 = *(const float4*)(qp2 + k);
            qA[k] = v0.x; qA[k + 1] = v0.y; qA[k + 2] = v0.z; qA[k + 3] = v0.w;
            qB[k] = v1.x; qB[k + 1] = v1.y; qB[k + 2] = v1.z; qB[k + 3] = v1.w;
        }
    }
    float ctxA[32], ctxB[32];
#pragma unroll
    for (int k = 0; k < 32; ++k) { ctxA[k] = 0.f; ctxB[k] = 0.f; }
    float mA = -1e30f, mB = -1e30f, lA = 0.f, lB = 0.f;

    const int lr = (tid & 127) >> 3;
    const int lc = (tid & 7) << 2;
    const bool loadV = (tid >= 128);

    for (int c = 0; c < T_ / 16; ++c) {
        const int s0 = c << 4;
        __syncthreads();
        {
            const float* src = qkv + ((size_t)(b * T_) + s0 + lr) * 768 +
                               (loadV ? 512 : 256) + h * KD_ + lc;
            float4 v = *(const float4*)src;
            if (loadV) *(float4*)&Vs[lr][lc] = v;
            else       *(float4*)&Ks[lr][lc] = v;
            if (tid < 16) mk[tid] = (seq[b * T_ + s0 + tid] != 0) ? 0.f : 1.f;
        }
        __syncthreads();

        float sA[16], sB[16];
#pragma unroll
        for (int s = 0; s < 16; ++s) {
            float dA = 0.f, dB = 0.f;
#pragma unroll
            for (int k = 0; k < 32; k += 4) {
                float4 k4 = *(const float4*)&Ks[s][k];
                dA = fmaf(k4.x, qA[k], dA); dA = fmaf(k4.y, qA[k + 1], dA);
                dA = fmaf(k4.z, qA[k + 2], dA); dA = fmaf(k4.w, qA[k + 3], dA);
                dB = fmaf(k4.x, qB[k], dB); dB = fmaf(k4.y, qB[k + 1], dB);
                dB = fmaf(k4.z, qB[k + 2], dB); dB = fmaf(k4.w, qB[k + 3], dB);
            }
            const float SCL = 0.17677669529663687f; // 1/sqrt(32)
            const bool masked = (mk[s] > 0.5f);
            sA[s] = masked ? NEG_ : dA * SCL;
            sB[s] = masked ? NEG_ : dB * SCL;
        }
        float cmA = sA[0], cmB = sB[0];
#pragma unroll
        for (int s = 1; s < 16; ++s) {
            cmA = fmaxf(cmA, sA[s]); cmB = fmaxf(cmB, sB[s]);
        }
        const float mnA = fmaxf(mA, cmA), mnB = fmaxf(mB, cmB);
        const float alA = __expf(mA - mnA), alB = __expf(mB - mnB);
        float psA = 0.f, psB = 0.f;
#pragma unroll
        for (int s = 0; s < 16; ++s) {
            float pa = __expf(sA[s] - mnA); sA[s] = pa; psA += pa;
            float pb = __expf(sB[s] - mnB); sB[s] = pb; psB += pb;
        }
        lA = fmaf(lA, alA, psA); lB = fmaf(lB, alB, psB);
        mA = mnA; mB = mnB;
#pragma unroll
        for (int k = 0; k < 32; ++k) { ctxA[k] *= alA; ctxB[k] *= alB; }
#pragma unroll
        for (int s = 0; s < 16; ++s) {
#pragma unroll
            for (int k = 0; k < 32; k += 4) {
                float4 v4 = *(const float4*)&Vs[s][k];
                ctxA[k]     = fmaf(sA[s], v4.x, ctxA[k]);
                ctxA[k + 1] = fmaf(sA[s], v4.y, ctxA[k + 1]);
                ctxA[k + 2] = fmaf(sA[s], v4.z, ctxA[k + 2]);
                ctxA[k + 3] = fmaf(sA[s], v4.w, ctxA[k + 3]);
                ctxB[k]     = fmaf(sB[s], v4.x, ctxB[k]);
                ctxB[k + 1] = fmaf(sB[s], v4.y, ctxB[k + 1]);
                ctxB[k + 2] = fmaf(sB[s], v4.z, ctxB[k + 2]);
                ctxB[k + 3] = fmaf(sB[s], v4.w, ctxB[k + 3]);
            }
        }
    }

    const float iA = 1.f / lA, iB = 1.f / lB;
    ushort_t* chA = cxh + (((size_t)(b * T_) + tid) * NH_ + h) * KD_;
    ushort_t* clA = cxl + (((size_t)(b * T_) + tid) * NH_ + h) * KD_;
    ushort_t* chB = chA + (size_t)256 * NH_ * KD_;
    ushort_t* clB = clA + (size_t)256 * NH_ * KD_;
#pragma unroll
    for (int k = 0; k < 32; ++k) {
        ushort_t hA, lA_, hB, lB_;
        split_bf16(ctxA[k] * iA, hA, lA_);
        split_bf16(ctxB[k] * iB, hB, lB_);
        chA[k] = hA; clA[k] = lA_;
        chB[k] = hB; clB[k] = lB_;
    }
}

// ---------------------------------------------------------------------------
// Fused masked avg/max pooling + MLP head. One WG per batch, 256 threads.
// ---------------------------------------------------------------------------
__global__ __launch_bounds__(256) void poolmlp_kernel(
    const int* __restrict__ seq, const float* __restrict__ att,
    const float* __restrict__ W1, const float* __restrict__ b1,
    const float* __restrict__ W2, const float* __restrict__ b2,
    const float* __restrict__ W3, const float* __restrict__ b3,
    float* __restrict__ out)
{
    const int b = blockIdx.x;
    const int tid = threadIdx.x;
    __shared__ float mk[T_];
    __shared__ float pl[512];
    __shared__ float x1l[256];
    __shared__ float x2l[128];

    for (int t = tid; t < T_; t += 256)
        mk[t] = (seq[b * T_ + t] != 0) ? 1.f : 0.f;
    __syncthreads();

    float sum = 0.f, mx = NEG_, cnt = 0.f;
    for (int t = 0; t < T_; ++t) {
        const float a = att[((size_t)b * T_ + t) * 256 + tid];
        const float m = mk[t];
        cnt += m;
        sum = fmaf(m, a, sum);
        mx = fmaxf(mx, (m > 0.5f) ? a : NEG_);
    }
    pl[tid] = sum / fmaxf(cnt, 1.f);
    pl[256 + tid] = mx;
    __syncthreads();

    {
        float acc = b1[tid];
        for (int k = 0; k < 512; ++k) acc = fmaf(pl[k], W1[k * 256 + tid], acc);
        x1l[tid] = fmaxf(acc, 0.f);
    }
    __syncthreads();
    if (tid < 128) {
        float acc = b2[tid];
        for (int k = 0; k < 256; ++k) acc = fmaf(x1l[k], W2[k * 128 + tid], acc);
        x2l[tid] = fmaxf(acc, 0.f);
    }
    __syncthreads();
    if (tid < 128) {
        float acc = b3[tid];
        for (int k = 0; k < 128; ++k) acc = fmaf(x2l[k], W3[k * 128 + tid], acc);
        out[b * 128 + tid] = acc;
    }
}

// ---------------------------------------------------------------------------
extern "C" void kernel_launch(void* const* d_in, const int* in_sizes, int n_in,
                              void* d_out, int out_size, void* d_ws, size_t ws_size,
                              hipStream_t stream)
{
    (void)in_sizes; (void)n_in; (void)out_size; (void)ws_size;
    const int*   seq = (const int*)d_in[0];
    const float* emb = (const float*)d_in[1];
    const float* Wf  = (const float*)d_in[2];
    const float* Uf  = (const float*)d_in[3];
    const float* bf  = (const float*)d_in[4];
    const float* Wb  = (const float*)d_in[5];
    const float* Ub  = (const float*)d_in[6];
    const float* bb  = (const float*)d_in[7];
    const float* Wq  = (const float*)d_in[8];
    const float* bq  = (const float*)d_in[9];
    const float* Wk  = (const float*)d_in[10];
    const float* bk  = (const float*)d_in[11];
    const float* Wv  = (const float*)d_in[12];
    const float* bv  = (const float*)d_in[13];
    const float* Wo  = (const float*)d_in[14];
    const float* bo  = (const float*)d_in[15];
    const float* W1  = (const float*)d_in[16];
    const float* b1  = (const float*)d_in[17];
    const float* W2  = (const float*)d_in[18];
    const float* b2  = (const float*)d_in[19];
    const float* W3  = (const float*)d_in[20];
    const float* b3  = (const float*)d_in[21];
    float* out = (float*)d_out;
    float* ws  = (float*)d_ws;

    // workspace layout (float offsets)
    float* qkv  = ws;                              // BT*768 f32 [0, 25165824)
    ushort_t* cxh = (ushort_t*)(ws + 25165824);    // BT*256 bf16-hi
    ushort_t* cxl = cxh + (size_t)BT_ * 256;       // BT*256 bf16-lo
    ushort_t* hch = (ushort_t*)(ws + 33554432);    // BT*256 bf16-hi (h)
    ushort_t* hcl = hch + (size_t)BT_ * 256;
    float* attb = ws + 33554432;                   // BT*256 f32 (over hch/hcl)
    ushort_t* wt = (ushort_t*)(ws + 41943040);
    ushort_t* wqkvh = wt;                          // 768*256
    ushort_t* wqkvl = wt + 196608;                 // 768*256
    ushort_t* woh   = wt + 393216;                 // 256*256
    ushort_t* wol   = wt + 458752;                 // 256*256
    float* embWf = ws + 41943040 + 262144;         // 20*512 f32
    float* embWb = embWf + 20 * 512;
    float* qkvb  = embWb + 20 * 512;               // 768 f32

    const dim3 blk256(256);

    // prep: weight splits + embW gather tables + stacked qkv bias
    prep_kernel<<<dim3(1029), blk256, 0, stream>>>(
        emb, Wf, bf, Wb, bb, Wq, Wk, Wv, Wo, bq, bk, bv,
        wqkvh, wqkvl, woh, wol, embWf, embWb, qkvb);

    // bidirectional LSTM scan -> h as bf16 hi/lo
    lstm_scan<<<dim3(128), dim3(1024), 0, stream>>>(
        seq, embWf, embWb, Uf, Ub, hch, hcl);

    // fused QKV projection (bf16x3 MFMA), N=768
    gemm_mfma3<<<dim3((BT_ / 128) * 6), blk256, 0, stream>>>(
        hch, hcl, wqkvh, wqkvl, qkvb, qkv, BT_, 768);

    // fused attention -> ctx as bf16 hi/lo
    attn_fused<<<dim3(B_ * NH_), blk256, 0, stream>>>(seq, qkv, cxh, cxl);

    // attention output projection (bf16x3 MFMA)
    gemm_mfma3<<<dim3((BT_ / 128) * 2), blk256, 0, stream>>>(
        cxh, cxl, woh, wol, bo, attb, BT_, 256);

    // masked pooling + MLP head (fused)
    poolmlp_kernel<<<dim3(B_), blk256, 0, stream>>>(
        seq, attb, W1, b1, W2, b2, W3, b3, out);
}

// Round 8
// 931.184 us; speedup vs baseline: 1.2569x; 1.2569x over previous
//
#include <hip/hip_runtime.h>
#include <math.h>

#define B_ 64
#define T_ 512
#define E_ 64
#define H_ 128
#define NH_ 8
#define KD_ 32
#define BT_ (B_ * T_)
#define NEG_ -1e9f

typedef __attribute__((ext_vector_type(8))) short bf16x8_t;
typedef __attribute__((ext_vector_type(4))) float f32x4_t;
typedef unsigned short ushort_t;
typedef unsigned int uint_t;

__device__ __forceinline__ float sigmoidf_(float x) {
    return 1.f / (1.f + __expf(-x));
}
__device__ __forceinline__ float tanhf_(float x) {
    return 1.f - 2.f / (1.f + __expf(2.f * x));
}

__device__ __forceinline__ ushort_t bf16_rne(float x) {
    uint_t u = __float_as_uint(x);
    uint_t r = (u + 0x7FFFu + ((u >> 16) & 1u)) >> 16;
    return (ushort_t)r;
}
__device__ __forceinline__ float bf16_to_f(ushort_t h) {
    return __uint_as_float(((uint_t)h) << 16);
}
__device__ __forceinline__ void split_bf16(float x, ushort_t& h, ushort_t& l) {
    h = bf16_rne(x);
    l = bf16_rne(x - bf16_to_f(h));
}

// DPP quad-perm lane swaps: xor1 = [1,0,3,2], xor2 = [2,3,0,1]
__device__ __forceinline__ float qswap1(float x) {
    return __int_as_float(__builtin_amdgcn_mov_dpp(__float_as_int(x), 0xB1, 0xF, 0xF, true));
}
__device__ __forceinline__ float qswap2(float x) {
    return __int_as_float(__builtin_amdgcn_mov_dpp(__float_as_int(x), 0x4E, 0xF, 0xF, true));
}

// ---------------------------------------------------------------------------
// Prep:
//  blk 0..1023   : weight transpose + bf16 hi/lo split.
//                  m = blk>>8: 0..2 -> Wq/Wk/Wv stacked; m==3 -> Wo.
//  blk 1024..1027: embW tables embW[v][jj*4+g] = (emb[v] @ W + b), unit-major.
//  blk 1028      : stacked qkv bias (bq|bk|bv).
// ---------------------------------------------------------------------------
__global__ void prep_kernel(
    const float* __restrict__ emb,
    const float* __restrict__ Wf, const float* __restrict__ bf,
    const float* __restrict__ Wb, const float* __restrict__ bb,
    const float* __restrict__ Wq, const float* __restrict__ Wk,
    const float* __restrict__ Wv, const float* __restrict__ Wo,
    const float* __restrict__ bq, const float* __restrict__ bk,
    const float* __restrict__ bv,
    ushort_t* __restrict__ wqkvh, ushort_t* __restrict__ wqkvl,
    ushort_t* __restrict__ woh, ushort_t* __restrict__ wol,
    float* __restrict__ embWf, float* __restrict__ embWb,
    float* __restrict__ qkvb)
{
    const int blk = blockIdx.x, tid = threadIdx.x;
    if (blk < 1024) {
        const int m = blk >> 8, k = blk & 255;
        const float* W = (m == 0) ? Wq : (m == 1) ? Wk : (m == 2) ? Wv : Wo;
        float v = W[k * 256 + tid];
        ushort_t h, l;
        split_bf16(v, h, l);
        if (m < 3) {
            wqkvh[(m * 256 + tid) * 256 + k] = h;
            wqkvl[(m * 256 + tid) * 256 + k] = l;
        } else {
            woh[tid * 256 + k] = h;
            wol[tid * 256 + k] = l;
        }
    } else if (blk < 1028) {
        const int e = blk - 1024;
        const int dir = e >> 1, half = e & 1;
        const float* W = dir ? Wb : Wf;
        const float* bias = dir ? bb : bf;
        float* dst = dir ? embWb : embWf;
        const int np = half * 256 + tid;          // output col 0..511
        const int gin = ((np & 3) << 7) + (np >> 2);
        for (int v = 0; v < 20; ++v) {
            float acc = bias[gin];
            for (int k = 0; k < 64; ++k)
                acc = fmaf(emb[v * 64 + k], W[k * 512 + gin], acc);
            dst[v * 512 + np] = acc;
        }
    } else {
        qkvb[tid] = bq[tid];
        qkvb[256 + tid] = bk[tid];
        qkvb[512 + tid] = bv[tid];
    }
}

// ---------------------------------------------------------------------------
// bf16x3 MFMA GEMM: C[M][N] = A@B + bias, K=256 fixed. (verified r4-r7)
// ---------------------------------------------------------------------------
__global__ __launch_bounds__(256, 2) void gemm_mfma3(
    const ushort_t* __restrict__ Ah, const ushort_t* __restrict__ Al,
    const ushort_t* __restrict__ Bh, const ushort_t* __restrict__ Bl,
    const float* __restrict__ bias, float* __restrict__ C,
    int M, int N)
{
    __shared__ __align__(16) ushort_t Alds[2][128 * 40];
    __shared__ __align__(16) ushort_t Blds[2][128 * 40];

    const int tid = threadIdx.x;
    const int ntn = N >> 7;
    const int bm = blockIdx.x / ntn, bn = blockIdx.x % ntn;
    const int m0 = bm << 7, n0 = bn << 7;

    const int w = tid >> 6;
    const int wr = w >> 1, wc = w & 1;
    const int lane = tid & 63;
    const int fr = lane & 15, kg = lane >> 4;

    const int sr = tid >> 1;
    const int sh = (tid & 1) << 4;

    f32x4_t acc[4][4];
#pragma unroll
    for (int i = 0; i < 4; ++i)
#pragma unroll
        for (int j = 0; j < 4; ++j) acc[i][j] = (f32x4_t){0.f, 0.f, 0.f, 0.f};

    for (int ks = 0; ks < 8; ++ks) {
        const int k0 = ks << 5;
        __syncthreads();
        {
            const size_t ga = (size_t)(m0 + sr) * 256 + k0 + sh;
            const size_t gb = (size_t)(n0 + sr) * 256 + k0 + sh;
            const int ld = sr * 40 + sh;
            const uint4* pah = (const uint4*)(Ah + ga);
            const uint4* pal = (const uint4*)(Al + ga);
            const uint4* pbh = (const uint4*)(Bh + gb);
            const uint4* pbl = (const uint4*)(Bl + gb);
            uint4* qah = (uint4*)&Alds[0][ld];
            uint4* qal = (uint4*)&Alds[1][ld];
            uint4* qbh = (uint4*)&Blds[0][ld];
            uint4* qbl = (uint4*)&Blds[1][ld];
            qah[0] = pah[0]; qah[1] = pah[1];
            qal[0] = pal[0]; qal[1] = pal[1];
            qbh[0] = pbh[0]; qbh[1] = pbh[1];
            qbl[0] = pbl[0]; qbl[1] = pbl[1];
        }
        __syncthreads();

        bf16x8_t ah[4], al[4], bh[4], bl[4];
#pragma unroll
        for (int i = 0; i < 4; ++i) {
            const int ra = (wr * 64 + i * 16 + fr) * 40 + kg * 8;
            const int rb = (wc * 64 + i * 16 + fr) * 40 + kg * 8;
            ah[i] = *(const bf16x8_t*)&Alds[0][ra];
            al[i] = *(const bf16x8_t*)&Alds[1][ra];
            bh[i] = *(const bf16x8_t*)&Blds[0][rb];
            bl[i] = *(const bf16x8_t*)&Blds[1][rb];
        }
#pragma unroll
        for (int i = 0; i < 4; ++i)
#pragma unroll
            for (int j = 0; j < 4; ++j) {
                acc[i][j] = __builtin_amdgcn_mfma_f32_16x16x32_bf16(
                    ah[i], bh[j], acc[i][j], 0, 0, 0);
                acc[i][j] = __builtin_amdgcn_mfma_f32_16x16x32_bf16(
                    ah[i], bl[j], acc[i][j], 0, 0, 0);
                acc[i][j] = __builtin_amdgcn_mfma_f32_16x16x32_bf16(
                    al[i], bh[j], acc[i][j], 0, 0, 0);
            }
    }

#pragma unroll
    for (int j = 0; j < 4; ++j) {
        const int col = n0 + wc * 64 + j * 16 + fr;
        const float bv = bias[col];
#pragma unroll
        for (int i = 0; i < 4; ++i) {
#pragma unroll
            for (int r = 0; r < 4; ++r) {
                const int row = m0 + wr * 64 + i * 16 + kg * 4 + r;
                C[(size_t)row * N + col] = acc[i][j][r] + bv;
            }
        }
    }
}

// ---------------------------------------------------------------------------
// Bidirectional LSTM scan. One WG per (batch, dir): 128 WGs, 512 threads.
// Thread (jj = tid>>2, ks = tid&3): 4 gates of unit jj over k-chunk
// [32ks, 32ks+32).
// KEY FIX (r1-r7 bottleneck): U elements are loaded ONCE via volatile
// inline-asm global_load_dword with "=v" outputs. Volatile asm results
// cannot be rematerialized/sunk, so the allocator must keep all 128 floats
// in arch VGPRs across the loop. (Before: compiler kept the loads inside
// the t-loop -> 256 KB/WG/step re-streamed from L2 = the invariant
// ~450-700 us floor; L1 is 32 KB so U never cached closer.)
// Raw lgkmcnt-only barrier: h global-stores + xw prefetch stay in flight
// (compiler's __syncthreads emits vmcnt(0) drain = r5 stall).
// ---------------------------------------------------------------------------
__global__ __launch_bounds__(512, 2) void lstm_scan(
    const int* __restrict__ seq,
    const float* __restrict__ embWf, const float* __restrict__ embWb,
    const float* __restrict__ Uf, const float* __restrict__ Ub,
    ushort_t* __restrict__ hch, ushort_t* __restrict__ hcl)
{
    const int w = blockIdx.x;
    const int dir = w & 1, b = w >> 1;
    const float* eW = dir ? embWb : embWf;
    const float* U  = dir ? Ub  : Uf;
    const int tid = threadIdx.x;
    const int jj = tid >> 2, ks = tid & 3;

    __shared__ __align__(16) float hbuf[2][4][36];  // slice ks = h[32ks..+32)
    __shared__ int tkl[T_];

    // --- pinned U block: u[g][kk] = U[32ks+kk][g*128+jj], 128 VGPRs ---
    float u[4][32];
    __builtin_amdgcn_sched_barrier(0);
#pragma unroll
    for (int g = 0; g < 4; ++g)
#pragma unroll
        for (int kk = 0; kk < 32; ++kk) {
            const float* p = U + (size_t)(32 * ks + kk) * 512 + g * 128 + jj;
            asm volatile("global_load_dword %0, %1, off"
                         : "=v"(u[g][kk]) : "v"(p));
        }
    asm volatile("s_waitcnt vmcnt(0)" ::: "memory");
    __builtin_amdgcn_sched_barrier(0);

    tkl[tid] = seq[b * T_ + tid];
    if (tid < 2 * 4 * 36) ((float*)hbuf)[tid] = 0.f;

    float h_cur = 0.f, c_cur = 0.f;
    ushort_t* hoh = hch + (size_t)b * T_ * 256 + dir * 128;
    ushort_t* hol = hcl + (size_t)b * T_ * 256 + dir * 128;

    __syncthreads();

    int te = dir ? (T_ - 1) : 0;
    int tok = tkl[te];
    float4 xwv = *(const float4*)&eW[tok * 512 + jj * 4];

    int p = 0;
    for (int t = 0; t < T_; ++t) {
        const int te_n  = dir ? (te - 1) : (te + 1);
        const int te_pf = (t == T_ - 1) ? te : te_n;
        const int tok_n = tkl[te_pf];
        const float4 xw_n = *(const float4*)&eW[tok_n * 512 + jj * 4];

        float a0 = 0.f, a1 = 0.f, a2 = 0.f, a3 = 0.f;
        const float* hc = hbuf[p][ks];
#pragma unroll
        for (int c = 0; c < 8; ++c) {
            const float4 h4 = *(const float4*)&hc[c * 4];
            a0 = fmaf(h4.x, u[0][c*4+0], a0); a0 = fmaf(h4.y, u[0][c*4+1], a0);
            a0 = fmaf(h4.z, u[0][c*4+2], a0); a0 = fmaf(h4.w, u[0][c*4+3], a0);
            a1 = fmaf(h4.x, u[1][c*4+0], a1); a1 = fmaf(h4.y, u[1][c*4+1], a1);
            a1 = fmaf(h4.z, u[1][c*4+2], a1); a1 = fmaf(h4.w, u[1][c*4+3], a1);
            a2 = fmaf(h4.x, u[2][c*4+0], a2); a2 = fmaf(h4.y, u[2][c*4+1], a2);
            a2 = fmaf(h4.z, u[2][c*4+2], a2); a2 = fmaf(h4.w, u[2][c*4+3], a2);
            a3 = fmaf(h4.x, u[3][c*4+0], a3); a3 = fmaf(h4.y, u[3][c*4+1], a3);
            a3 = fmaf(h4.z, u[3][c*4+2], a3); a3 = fmaf(h4.w, u[3][c*4+3], a3);
        }
        // 4-lane butterfly (pure DPP, VALU pipe)
        a0 += qswap1(a0); a0 += qswap2(a0);
        a1 += qswap1(a1); a1 += qswap2(a1);
        a2 += qswap1(a2); a2 += qswap2(a2);
        a3 += qswap1(a3); a3 += qswap2(a3);

        const float zi = xwv.x + a0, zf = xwv.y + a1;
        const float zg = xwv.z + a2, zo = xwv.w + a3;
        const float cn = fmaf(sigmoidf_(zf), c_cur, sigmoidf_(zi) * tanhf_(zg));
        const float hn = sigmoidf_(zo) * tanhf_(cn);
        const bool mt = (tok != 0);
        const float hm = mt ? hn : h_cur;
        c_cur = mt ? cn : c_cur;
        h_cur = hm;

        if ((jj >> 5) == ks) hbuf[1 - p][ks][jj & 31] = hm;
        if (ks == 0) {
            ushort_t hh, hl;
            split_bf16(hm, hh, hl);
            hoh[(size_t)te * 256 + jj] = hh;
            hol[(size_t)te * 256 + jj] = hl;
        }
        // LDS-only drain + barrier: global stores/prefetch stay in flight.
        asm volatile("s_waitcnt lgkmcnt(0)\n\ts_barrier" ::: "memory");
        p ^= 1; te = te_n; tok = tok_n; xwv = xw_n;
    }
}

// ---------------------------------------------------------------------------
// Fused flash-style attention. One WG per (b, head): 512 WGs, 256 threads.
// q/k/v packed in one [BT][768] buffer (cols: q 0..255, k 256..511, v 512..).
// ---------------------------------------------------------------------------
__global__ __launch_bounds__(256, 2) void attn_fused(
    const int* __restrict__ seq,
    const float* __restrict__ qkv,
    ushort_t* __restrict__ cxh, ushort_t* __restrict__ cxl)
{
    const int wg = blockIdx.x;
    const int b = wg >> 3, h = wg & 7;
    const int tid = threadIdx.x;

    __shared__ __align__(16) float Ks[16][32];
    __shared__ __align__(16) float Vs[16][32];
    __shared__ float mk[16];

    float qA[32], qB[32];
    {
        const float* qp  = qkv + ((size_t)(b * T_) + tid) * 768 + h * KD_;
        const float* qp2 = qp + (size_t)256 * 768;
#pragma unroll
        for (int k = 0; k < 32; k += 4) {
            float4 v0 = *(const float4*)(qp + k);
            float4 v1 = *(const float4*)(qp2 + k);
            qA[k] = v0.x; qA[k + 1] = v0.y; qA[k + 2] = v0.z; qA[k + 3] = v0.w;
            qB[k] = v1.x; qB[k + 1] = v1.y; qB[k + 2] = v1.z; qB[k + 3] = v1.w;
        }
    }
    float ctxA[32], ctxB[32];
#pragma unroll
    for (int k = 0; k < 32; ++k) { ctxA[k] = 0.f; ctxB[k] = 0.f; }
    float mA = -1e30f, mB = -1e30f, lA = 0.f, lB = 0.f;

    const int lr = (tid & 127) >> 3;
    const int lc = (tid & 7) << 2;
    const bool loadV = (tid >= 128);

    for (int c = 0; c < T_ / 16; ++c) {
        const int s0 = c << 4;
        __syncthreads();
        {
            const float* src = qkv + ((size_t)(b * T_) + s0 + lr) * 768 +
                               (loadV ? 512 : 256) + h * KD_ + lc;
            float4 v = *(const float4*)src;
            if (loadV) *(float4*)&Vs[lr][lc] = v;
            else       *(float4*)&Ks[lr][lc] = v;
            if (tid < 16) mk[tid] = (seq[b * T_ + s0 + tid] != 0) ? 0.f : 1.f;
        }
        __syncthreads();

        float sA[16], sB[16];
#pragma unroll
        for (int s = 0; s < 16; ++s) {
            float dA = 0.f, dB = 0.f;
#pragma unroll
            for (int k = 0; k < 32; k += 4) {
                float4 k4 = *(const float4*)&Ks[s][k];
                dA = fmaf(k4.x, qA[k], dA); dA = fmaf(k4.y, qA[k + 1], dA);
                dA = fmaf(k4.z, qA[k + 2], dA); dA = fmaf(k4.w, qA[k + 3], dA);
                dB = fmaf(k4.x, qB[k], dB); dB = fmaf(k4.y, qB[k + 1], dB);
                dB = fmaf(k4.z, qB[k + 2], dB); dB = fmaf(k4.w, qB[k + 3], dB);
            }
            const float SCL = 0.17677669529663687f; // 1/sqrt(32)
            const bool masked = (mk[s] > 0.5f);
            sA[s] = masked ? NEG_ : dA * SCL;
            sB[s] = masked ? NEG_ : dB * SCL;
        }
        float cmA = sA[0], cmB = sB[0];
#pragma unroll
        for (int s = 1; s < 16; ++s) {
            cmA = fmaxf(cmA, sA[s]); cmB = fmaxf(cmB, sB[s]);
        }
        const float mnA = fmaxf(mA, cmA), mnB = fmaxf(mB, cmB);
        const float alA = __expf(mA - mnA), alB = __expf(mB - mnB);
        float psA = 0.f, psB = 0.f;
#pragma unroll
        for (int s = 0; s < 16; ++s) {
            float pa = __expf(sA[s] - mnA); sA[s] = pa; psA += pa;
            float pb = __expf(sB[s] - mnB); sB[s] = pb; psB += pb;
        }
        lA = fmaf(lA, alA, psA); lB = fmaf(lB, alB, psB);
        mA = mnA; mB = mnB;
#pragma unroll
        for (int k = 0; k < 32; ++k) { ctxA[k] *= alA; ctxB[k] *= alB; }
#pragma unroll
        for (int s = 0; s < 16; ++s) {
#pragma unroll
            for (int k = 0; k < 32; k += 4) {
                float4 v4 = *(const float4*)&Vs[s][k];
                ctxA[k]     = fmaf(sA[s], v4.x, ctxA[k]);
                ctxA[k + 1] = fmaf(sA[s], v4.y, ctxA[k + 1]);
                ctxA[k + 2] = fmaf(sA[s], v4.z, ctxA[k + 2]);
                ctxA[k + 3] = fmaf(sA[s], v4.w, ctxA[k + 3]);
                ctxB[k]     = fmaf(sB[s], v4.x, ctxB[k]);
                ctxB[k + 1] = fmaf(sB[s], v4.y, ctxB[k + 1]);
                ctxB[k + 2] = fmaf(sB[s], v4.z, ctxB[k + 2]);
                ctxB[k + 3] = fmaf(sB[s], v4.w, ctxB[k + 3]);
            }
        }
    }

    const float iA = 1.f / lA, iB = 1.f / lB;
    ushort_t* chA = cxh + (((size_t)(b * T_) + tid) * NH_ + h) * KD_;
    ushort_t* clA = cxl + (((size_t)(b * T_) + tid) * NH_ + h) * KD_;
    ushort_t* chB = chA + (size_t)256 * NH_ * KD_;
    ushort_t* clB = clA + (size_t)256 * NH_ * KD_;
#pragma unroll
    for (int k = 0; k < 32; ++k) {
        ushort_t hA, lA_, hB, lB_;
        split_bf16(ctxA[k] * iA, hA, lA_);
        split_bf16(ctxB[k] * iB, hB, lB_);
        chA[k] = hA; clA[k] = lA_;
        chB[k] = hB; clB[k] = lB_;
    }
}

// ---------------------------------------------------------------------------
// Fused masked avg/max pooling + MLP head. One WG per batch, 256 threads.
// ---------------------------------------------------------------------------
__global__ __launch_bounds__(256) void poolmlp_kernel(
    const int* __restrict__ seq, const float* __restrict__ att,
    const float* __restrict__ W1, const float* __restrict__ b1,
    const float* __restrict__ W2, const float* __restrict__ b2,
    const float* __restrict__ W3, const float* __restrict__ b3,
    float* __restrict__ out)
{
    const int b = blockIdx.x;
    const int tid = threadIdx.x;
    __shared__ float mk[T_];
    __shared__ float pl[512];
    __shared__ float x1l[256];
    __shared__ float x2l[128];

    for (int t = tid; t < T_; t += 256)
        mk[t] = (seq[b * T_ + t] != 0) ? 1.f : 0.f;
    __syncthreads();

    float sum = 0.f, mx = NEG_, cnt = 0.f;
    for (int t = 0; t < T_; ++t) {
        const float a = att[((size_t)b * T_ + t) * 256 + tid];
        const float m = mk[t];
        cnt += m;
        sum = fmaf(m, a, sum);
        mx = fmaxf(mx, (m > 0.5f) ? a : NEG_);
    }
    pl[tid] = sum / fmaxf(cnt, 1.f);
    pl[256 + tid] = mx;
    __syncthreads();

    {
        float acc = b1[tid];
        for (int k = 0; k < 512; ++k) acc = fmaf(pl[k], W1[k * 256 + tid], acc);
        x1l[tid] = fmaxf(acc, 0.f);
    }
    __syncthreads();
    if (tid < 128) {
        float acc = b2[tid];
        for (int k = 0; k < 256; ++k) acc = fmaf(x1l[k], W2[k * 128 + tid], acc);
        x2l[tid] = fmaxf(acc, 0.f);
    }
    __syncthreads();
    if (tid < 128) {
        float acc = b3[tid];
        for (int k = 0; k < 128; ++k) acc = fmaf(x2l[k], W3[k * 128 + tid], acc);
        out[b * 128 + tid] = acc;
    }
}

// ---------------------------------------------------------------------------
extern "C" void kernel_launch(void* const* d_in, const int* in_sizes, int n_in,
                              void* d_out, int out_size, void* d_ws, size_t ws_size,
                              hipStream_t stream)
{
    (void)in_sizes; (void)n_in; (void)out_size; (void)ws_size;
    const int*   seq = (const int*)d_in[0];
    const float* emb = (const float*)d_in[1];
    const float* Wf  = (const float*)d_in[2];
    const float* Uf  = (const float*)d_in[3];
    const float* bf  = (const float*)d_in[4];
    const float* Wb  = (const float*)d_in[5];
    const float* Ub  = (const float*)d_in[6];
    const float* bb  = (const float*)d_in[7];
    const float* Wq  = (const float*)d_in[8];
    const float* bq  = (const float*)d_in[9];
    const float* Wk  = (const float*)d_in[10];
    const float* bk  = (const float*)d_in[11];
    const float* Wv  = (const float*)d_in[12];
    const float* bv  = (const float*)d_in[13];
    const float* Wo  = (const float*)d_in[14];
    const float* bo  = (const float*)d_in[15];
    const float* W1  = (const float*)d_in[16];
    const float* b1  = (const float*)d_in[17];
    const float* W2  = (const float*)d_in[18];
    const float* b2  = (const float*)d_in[19];
    const float* W3  = (const float*)d_in[20];
    const float* b3  = (const float*)d_in[21];
    float* out = (float*)d_out;
    float* ws  = (float*)d_ws;

    // workspace layout (float offsets)
    float* qkv  = ws;                              // BT*768 f32 [0, 25165824)
    ushort_t* cxh = (ushort_t*)(ws + 25165824);    // BT*256 bf16-hi
    ushort_t* cxl = cxh + (size_t)BT_ * 256;       // BT*256 bf16-lo
    ushort_t* hch = (ushort_t*)(ws + 33554432);    // BT*256 bf16-hi (h)
    ushort_t* hcl = hch + (size_t)BT_ * 256;
    float* attb = ws + 33554432;                   // BT*256 f32 (over hch/hcl)
    ushort_t* wt = (ushort_t*)(ws + 41943040);
    ushort_t* wqkvh = wt;                          // 768*256
    ushort_t* wqkvl = wt + 196608;                 // 768*256
    ushort_t* woh   = wt + 393216;                 // 256*256
    ushort_t* wol   = wt + 458752;                 // 256*256
    float* embWf = ws + 41943040 + 262144;         // 20*512 f32
    float* embWb = embWf + 20 * 512;
    float* qkvb  = embWb + 20 * 512;               // 768 f32

    const dim3 blk256(256);

    // prep: weight splits + embW gather tables + stacked qkv bias
    prep_kernel<<<dim3(1029), blk256, 0, stream>>>(
        emb, Wf, bf, Wb, bb, Wq, Wk, Wv, Wo, bq, bk, bv,
        wqkvh, wqkvl, woh, wol, embWf, embWb, qkvb);

    // bidirectional LSTM scan -> h as bf16 hi/lo
    lstm_scan<<<dim3(128), dim3(512), 0, stream>>>(
        seq, embWf, embWb, Uf, Ub, hch, hcl);

    // fused QKV projection (bf16x3 MFMA), N=768
    gemm_mfma3<<<dim3((BT_ / 128) * 6), blk256, 0, stream>>>(
        hch, hcl, wqkvh, wqkvl, qkvb, qkv, BT_, 768);

    // fused attention -> ctx as bf16 hi/lo
    attn_fused<<<dim3(B_ * NH_), blk256, 0, stream>>>(seq, qkv, cxh, cxl);

    // attention output projection (bf16x3 MFMA)
    gemm_mfma3<<<dim3((BT_ / 128) * 2), blk256, 0, stream>>>(
        cxh, cxl, woh, wol, bo, attb, BT_, 256);

    // masked pooling + MLP head (fused)
    poolmlp_kernel<<<dim3(B_), blk256, 0, stream>>>(
        seq, attb, W1, b1, W2, b2, W3, b3, out);
}